// Round 1
// baseline (560.906 us; speedup 1.0000x reference)
//
#include <hip/hip_runtime.h>

// ---------------------------------------------------------------------------
// 2-layer GCN on MI355X.
// Algebra: GCNConv(x) = A_hat (x W) + b = (A_hat x) W + b  (aggregation and
// linear commute). Embedding lookup commutes with @W1:
//   emb[labels] @ W1 == (emb @ W1)[labels]  -> layer 1 gathers from a 512KB
// table (L2-resident) and needs no N-sized GEMM.
// Aggregation: CSR-by-dst built per call (deterministic work), gather-based
// (no float atomics). One wave per node, 2 features per lane (float2).
// ---------------------------------------------------------------------------

__global__ void init_kernel(float* __restrict__ deg, int* __restrict__ cnt, int n) {
  int i = blockIdx.x * blockDim.x + threadIdx.x;
  if (i < n) { deg[i] = 1.0f; cnt[i] = 0; }  // deg starts at 1.0: self-loop weight
}

__global__ void edge_deg_kernel(const int* __restrict__ dst, const float* __restrict__ w,
                                float* __restrict__ deg, int* __restrict__ cnt, int e) {
  int i = blockIdx.x * blockDim.x + threadIdx.x;
  if (i < e) {
    int d = dst[i];
    atomicAdd(&deg[d], w[i]);
    atomicAdd(&cnt[d], 1);
  }
}

__global__ void dinv_kernel(float* __restrict__ deg, int n) {
  int i = blockIdx.x * blockDim.x + threadIdx.x;
  if (i < n) deg[i] = rsqrtf(deg[i]);  // deg >= 1.0 always (self loop)
}

// Single-block scan over n counts -> exclusive prefix (row_start), also
// initializes cursor. Wave-level shfl scans: ~3 barriers per 1024 chunk.
__global__ __launch_bounds__(1024) void scan_kernel(const int* __restrict__ cnt,
                                                    int* __restrict__ row_start,
                                                    int* __restrict__ cursor, int n) {
  __shared__ int wsum[16];
  __shared__ int carry_s;
  int tid = threadIdx.x;
  int lane = tid & 63, wv = tid >> 6;
  if (tid == 0) carry_s = 0;
  __syncthreads();
  for (int base = 0; base < n; base += 1024) {
    int idx = base + tid;
    int v = (idx < n) ? cnt[idx] : 0;
    int x = v;
#pragma unroll
    for (int d = 1; d < 64; d <<= 1) {
      int t = __shfl_up(x, d, 64);
      if (lane >= d) x += t;
    }
    if (lane == 63) wsum[wv] = x;
    __syncthreads();
    int woff = 0;
#pragma unroll
    for (int w2 = 0; w2 < 16; ++w2) woff += (w2 < wv) ? wsum[w2] : 0;
    int carry = carry_s;
    int incl = x + woff;
    int excl = carry + incl - v;
    if (idx < n) { row_start[idx] = excl; cursor[idx] = excl; }
    __syncthreads();
    if (tid == 1023) carry_s = carry + incl;
    __syncthreads();
  }
  if (tid == 0) row_start[n] = carry_s;
}

__global__ void scatter_kernel(const int* __restrict__ src, const int* __restrict__ dst,
                               const float* __restrict__ w, const float* __restrict__ dinv,
                               int* __restrict__ cursor, int* __restrict__ csr_src,
                               float* __restrict__ csr_val, int e) {
  int i = blockIdx.x * blockDim.x + threadIdx.x;
  if (i < e) {
    int s = src[i], d = dst[i];
    int pos = atomicAdd(&cursor[d], 1);
    csr_src[pos] = s;
    csr_val[pos] = dinv[s] * w[i];  // prescale by dinv[src]; dinv[dst] applied per node
  }
}

// temb = emb_table @ W1   (vocab x 128) -- tiny GEMM
__global__ void temb_kernel(const float* __restrict__ emb, const float* __restrict__ W1,
                            float* __restrict__ temb) {
  int r = blockIdx.x, j = threadIdx.x;
  __shared__ float xs[128];
  xs[j] = emb[r * 128 + j];
  __syncthreads();
  float acc = 0.f;
#pragma unroll 8
  for (int k = 0; k < 128; ++k) acc = fmaf(xs[k], W1[k * 128 + j], acc);
  temb[r * 128 + j] = acc;
}

// One wave per node; lane owns features [2*lane, 2*lane+1].
// L1: gather h=temb via labels[src], add b1, relu. L2: gather h directly, add b2.
template <bool L1>
__global__ __launch_bounds__(256) void agg_kernel(
    const int* __restrict__ row_start, const int* __restrict__ csr_src,
    const float* __restrict__ csr_val, const float* __restrict__ dinv,
    const int* __restrict__ labels, const float* __restrict__ h,
    const float* __restrict__ bias, float* __restrict__ out, int n) {
  int wid = (blockIdx.x * blockDim.x + threadIdx.x) >> 6;
  int lane = threadIdx.x & 63;
  if (wid >= n) return;
  float di = dinv[wid];
  size_t self_row = L1 ? (size_t)labels[wid] : (size_t)wid;
  float2 hv = *(const float2*)(h + self_row * 128 + 2 * lane);
  float acc0 = hv.x * di, acc1 = hv.y * di;  // self term (x di again at the end)
  int e1 = row_start[wid + 1];
  for (int base = row_start[wid]; base < e1; base += 64) {
    int s = 0; float v = 0.f;
    if (base + lane < e1) {
      s = csr_src[base + lane];
      v = csr_val[base + lane];
      if (L1) s = labels[s];
    }
    int nb = min(64, e1 - base);
    for (int j = 0; j < nb; ++j) {
      int sj = __shfl(s, j, 64);
      float vj = __shfl(v, j, 64);
      const float2 hs = *(const float2*)(h + (size_t)sj * 128 + 2 * lane);
      acc0 = fmaf(hs.x, vj, acc0);
      acc1 = fmaf(hs.y, vj, acc1);
    }
  }
  acc0 = fmaf(acc0, di, bias[2 * lane]);
  acc1 = fmaf(acc1, di, bias[2 * lane + 1]);
  if (L1) { acc0 = fmaxf(acc0, 0.f); acc1 = fmaxf(acc1, 0.f); }
  *(float2*)(out + (size_t)wid * 128 + 2 * lane) = make_float2(acc0, acc1);
}

// y[n,128] = x[n,128] @ W[128,128]. Block: 32 rows, 256 thr = (32 colgrp x 8 rowgrp),
// thread computes 4 rows x 4 cols. x tile staged in LDS (16KB); W streamed (L1/L2-hit).
__global__ __launch_bounds__(256) void gemm_kernel(const float* __restrict__ x,
                                                   const float* __restrict__ W,
                                                   float* __restrict__ y, int n) {
  __shared__ float xs[32][128];
  int tid = threadIdx.x;
  int tc = tid & 31;
  int tr = tid >> 5;
  int rb = blockIdx.x * 32;
  {
    const float4* xg = (const float4*)(x + (size_t)rb * 128);
    float4* xls = (float4*)&xs[0][0];
#pragma unroll
    for (int i = 0; i < 4; ++i) {
      int idx = tid + i * 256;       // float4 index; row = idx>>5
      int row = rb + (idx >> 5);
      float4 val = (row < n) ? xg[idx] : make_float4(0.f, 0.f, 0.f, 0.f);
      xls[idx] = val;
    }
  }
  __syncthreads();
  float acc[4][4] = {};
  int j0 = tc * 4;
#pragma unroll 4
  for (int k = 0; k < 128; ++k) {
    float4 w4 = *(const float4*)(W + k * 128 + j0);
#pragma unroll
    for (int r = 0; r < 4; ++r) {
      float xv = xs[tr * 4 + r][k];
      acc[r][0] = fmaf(xv, w4.x, acc[r][0]);
      acc[r][1] = fmaf(xv, w4.y, acc[r][1]);
      acc[r][2] = fmaf(xv, w4.z, acc[r][2]);
      acc[r][3] = fmaf(xv, w4.w, acc[r][3]);
    }
  }
#pragma unroll
  for (int r = 0; r < 4; ++r) {
    int row = rb + tr * 4 + r;
    if (row < n)
      *(float4*)(y + (size_t)row * 128 + j0) =
          make_float4(acc[r][0], acc[r][1], acc[r][2], acc[r][3]);
  }
}

extern "C" void kernel_launch(void* const* d_in, const int* in_sizes, int n_in,
                              void* d_out, int out_size, void* d_ws, size_t ws_size,
                              hipStream_t stream) {
  const int* labels = (const int*)d_in[0];
  const int* edge_index = (const int*)d_in[1];
  const float* weight = (const float*)d_in[2];
  const float* emb = (const float*)d_in[3];
  const float* W1 = (const float*)d_in[4];
  const float* b1 = (const float*)d_in[5];
  const float* W2 = (const float*)d_in[6];
  const float* b2 = (const float*)d_in[7];

  int n = in_sizes[0];
  int e = in_sizes[1] / 2;
  int vocab = in_sizes[3] / 128;
  const int* srcp = edge_index;
  const int* dstp = edge_index + e;

  // workspace carve-up (elements, 256-aligned). Total ~62.3 MiB.
  float* ws = (float*)d_ws;
  size_t o = 0;
  auto alloc_f = [&](size_t c) { float* p = ws + o; o += (c + 255) & ~(size_t)255; return p; };
  float* deg       = alloc_f(n);            // becomes dinv in-place
  int*   cnt       = (int*)alloc_f(n);
  int*   row_start = (int*)alloc_f(n + 1);
  int*   cursor    = (int*)alloc_f(n);
  int*   csr_src_b = (int*)alloc_f(e);
  float* csr_val   = alloc_f(e);
  float* temb      = alloc_f((size_t)vocab * 128);
  float* out1      = alloc_f((size_t)n * 128);
  float* h2        = alloc_f((size_t)n * 128);
  (void)ws_size;

  dim3 b256(256);
  int gn = (n + 255) / 256;
  int ge = (e + 255) / 256;
  int gagg = (int)(((size_t)n * 64 + 255) / 256);

  init_kernel<<<gn, b256, 0, stream>>>(deg, cnt, n);
  edge_deg_kernel<<<ge, b256, 0, stream>>>(dstp, weight, deg, cnt, e);
  dinv_kernel<<<gn, b256, 0, stream>>>(deg, n);
  scan_kernel<<<1, 1024, 0, stream>>>(cnt, row_start, cursor, n);
  scatter_kernel<<<ge, b256, 0, stream>>>(srcp, dstp, weight, deg, cursor,
                                          csr_src_b, csr_val, e);
  temb_kernel<<<vocab, 128, 0, stream>>>(emb, W1, temb);
  // layer 1: out1 = relu(A_hat temb[labels] + b1)
  agg_kernel<true><<<gagg, b256, 0, stream>>>(row_start, csr_src_b, csr_val, deg,
                                              labels, temb, b1, out1, n);
  // layer 2: h2 = out1 @ W2 ; d_out = A_hat h2 + b2
  gemm_kernel<<<(n + 31) / 32, b256, 0, stream>>>(out1, W2, h2, n);
  agg_kernel<false><<<gagg, b256, 0, stream>>>(row_start, csr_src_b, csr_val, deg,
                                               labels, h2, b2, (float*)d_out, n);
}

// Round 2
// 352.858 us; speedup vs baseline: 1.5896x; 1.5896x over previous
//
#include <hip/hip_runtime.h>

// ---------------------------------------------------------------------------
// 2-layer GCN on MI355X.
//   out = A_hat( relu( A_hat(emb[labels]) @ W1' ... ) ) -- using algebra:
//   GCNConv(x) = A_hat (x W) + b = (A_hat x) W + b, and emb[labels]@W1 =
//   (emb@W1)[labels]. Layer1 gathers from a 512KB L2-resident table.
// CSR build: single int-atomic pass (rank = within-row index), two-level
// scan, atomic-free placement. Weighted degree computed from CSR rows
// (no float atomics). Layer2: agg first, then in-place GEMM on d_out.
// ---------------------------------------------------------------------------

__global__ void init_kernel(int* __restrict__ cnt, int n) {
  int i = blockIdx.x * blockDim.x + threadIdx.x;
  if (i < n) cnt[i] = 0;
}

// rank[i] = arrival index of edge i within its dst row; cnt -> histogram.
__global__ void rank_kernel(const int* __restrict__ dst, int* __restrict__ cnt,
                            int* __restrict__ rank, int e) {
  int i = blockIdx.x * blockDim.x + threadIdx.x;
  if (i < e) rank[i] = atomicAdd(&cnt[dst[i]], 1);
}

// --- two-level exclusive scan of cnt[n] -> rs[n+1] ---
__global__ __launch_bounds__(256) void scan_a(const int* __restrict__ cnt,
                                              int* __restrict__ rs,
                                              int* __restrict__ bsum, int n) {
  __shared__ int wsum[4];
  int t = threadIdx.x, i = blockIdx.x * 256 + t;
  int lane = t & 63, wv = t >> 6;
  int v = (i < n) ? cnt[i] : 0;
  int x = v;
#pragma unroll
  for (int d = 1; d < 64; d <<= 1) {
    int tt = __shfl_up(x, d, 64);
    if (lane >= d) x += tt;
  }
  if (lane == 63) wsum[wv] = x;
  __syncthreads();
  int off = 0;
#pragma unroll
  for (int w = 0; w < 4; ++w) off += (w < wv) ? wsum[w] : 0;
  int excl = x - v + off;
  if (i < n) rs[i] = excl;
  if (t == 255) bsum[blockIdx.x] = excl + v;
}

__global__ __launch_bounds__(256) void scan_b(int* __restrict__ bsum, int nb) {
  __shared__ int wsum[4];
  int t = threadIdx.x;
  int lane = t & 63, wv = t >> 6;
  int v = (t < nb) ? bsum[t] : 0;
  int x = v;
#pragma unroll
  for (int d = 1; d < 64; d <<= 1) {
    int tt = __shfl_up(x, d, 64);
    if (lane >= d) x += tt;
  }
  if (lane == 63) wsum[wv] = x;
  __syncthreads();
  int off = 0;
#pragma unroll
  for (int w = 0; w < 4; ++w) off += (w < wv) ? wsum[w] : 0;
  if (t < nb) bsum[t] = x - v + off;
}

__global__ void scan_c(const int* __restrict__ bsum, int* __restrict__ rs,
                       int n, int e) {
  int i = blockIdx.x * blockDim.x + threadIdx.x;
  if (i < n) rs[i] += bsum[i >> 8];
  if (i == 0) rs[n] = e;
}

// place edge i at rs[dst]+rank[i]; csr entry = {src, w_bits}. No atomics.
__global__ void place_kernel(const int* __restrict__ src, const int* __restrict__ dst,
                             const float* __restrict__ w, const int* __restrict__ rank,
                             const int* __restrict__ rs, int2* __restrict__ csr, int e) {
  int i = blockIdx.x * blockDim.x + threadIdx.x;
  if (i < e) {
    int pos = rs[dst[i]] + rank[i];
    csr[pos] = make_int2(src[i], __float_as_int(w[i]));
  }
}

// dinv[d] = rsqrt(1 + sum_w over row d)  (contiguous reads, wave per node)
__global__ __launch_bounds__(256) void deg_kernel(const int* __restrict__ rs,
                                                  const int2* __restrict__ csr,
                                                  float* __restrict__ dinv, int n) {
  int wid = (blockIdx.x * blockDim.x + threadIdx.x) >> 6;
  int lane = threadIdx.x & 63;
  if (wid >= n) return;
  int r0 = rs[wid], r1 = rs[wid + 1];
  float s = 0.f;
  for (int i = r0 + lane; i < r1; i += 64) s += __int_as_float(csr[i].y);
#pragma unroll
  for (int d = 1; d < 64; d <<= 1) s += __shfl_xor(s, d, 64);
  if (lane == 0) dinv[wid] = rsqrtf(1.0f + s);
}

// csr.w *= dinv[src]  (prescale; dinv[dst] applied per node in agg)
__global__ void scale_kernel(int2* __restrict__ csr, const float* __restrict__ dinv, int e) {
  int i = blockIdx.x * blockDim.x + threadIdx.x;
  if (i < e) {
    int2 c = csr[i];
    c.y = __float_as_int(__int_as_float(c.y) * dinv[c.x]);
    csr[i] = c;
  }
}

// temb = emb_table @ W1   (vocab x 128) -- tiny GEMM
__global__ void temb_kernel(const float* __restrict__ emb, const float* __restrict__ W1,
                            float* __restrict__ temb) {
  int r = blockIdx.x, j = threadIdx.x;
  __shared__ float xs[128];
  xs[j] = emb[r * 128 + j];
  __syncthreads();
  float acc = 0.f;
#pragma unroll 8
  for (int k = 0; k < 128; ++k) acc = fmaf(xs[k], W1[k * 128 + j], acc);
  temb[r * 128 + j] = acc;
}

// One wave per node; lane owns features [2*lane, 2*lane+1].
// L1: gather h=temb via labels[src], +b1, relu. else: plain aggregate (no bias).
template <bool L1>
__global__ __launch_bounds__(256) void agg_kernel(
    const int* __restrict__ rs, const int2* __restrict__ csr,
    const float* __restrict__ dinv, const int* __restrict__ labels,
    const float* __restrict__ h, const float* __restrict__ bias,
    float* __restrict__ out, int n) {
  int wid = (blockIdx.x * blockDim.x + threadIdx.x) >> 6;
  int lane = threadIdx.x & 63;
  if (wid >= n) return;
  float di = dinv[wid];
  size_t self_row = L1 ? (size_t)labels[wid] : (size_t)wid;
  float2 hv = *(const float2*)(h + self_row * 128 + 2 * lane);
  float acc0 = hv.x * di, acc1 = hv.y * di;  // self term (x di again at end)
  int e1 = rs[wid + 1];
  for (int base = rs[wid]; base < e1; base += 64) {
    int s = 0;
    float v = 0.f;
    if (base + lane < e1) {
      int2 c = csr[base + lane];
      s = c.x;
      v = __int_as_float(c.y);
      if (L1) s = labels[s];
    }
    int nb = min(64, e1 - base);
    for (int j = 0; j < nb; ++j) {
      int sj = __shfl(s, j, 64);
      float vj = __shfl(v, j, 64);
      const float2 hs = *(const float2*)(h + (size_t)sj * 128 + 2 * lane);
      acc0 = fmaf(hs.x, vj, acc0);
      acc1 = fmaf(hs.y, vj, acc1);
    }
  }
  if (L1) {
    acc0 = fmaf(acc0, di, bias[2 * lane]);
    acc1 = fmaf(acc1, di, bias[2 * lane + 1]);
    acc0 = fmaxf(acc0, 0.f);
    acc1 = fmaxf(acc1, 0.f);
  } else {
    acc0 *= di;
    acc1 *= di;
  }
  *(float2*)(out + (size_t)wid * 128 + 2 * lane) = make_float2(acc0, acc1);
}

// In-place: y[rb..rb+31] = y[rb..rb+31] @ W + b. Each block only touches its
// own 32 rows (staged to LDS before overwrite) -> in-place safe.
__global__ __launch_bounds__(256) void gemm_bias_kernel(float* __restrict__ y,
                                                        const float* __restrict__ W,
                                                        const float* __restrict__ bias,
                                                        int n) {
  __shared__ float xs[32][128];
  int tid = threadIdx.x;
  int tc = tid & 31;
  int tr = tid >> 5;
  int rb = blockIdx.x * 32;
  {
    const float4* xg = (const float4*)(y + (size_t)rb * 128);
    float4* xls = (float4*)&xs[0][0];
#pragma unroll
    for (int i = 0; i < 4; ++i) {
      int idx = tid + i * 256;  // float4 index; row = idx>>5
      int row = rb + (idx >> 5);
      float4 val = (row < n) ? xg[idx] : make_float4(0.f, 0.f, 0.f, 0.f);
      xls[idx] = val;
    }
  }
  __syncthreads();
  int j0 = tc * 4;
  float4 b4 = *(const float4*)(bias + j0);
  float acc[4][4];
#pragma unroll
  for (int r = 0; r < 4; ++r) {
    acc[r][0] = b4.x; acc[r][1] = b4.y; acc[r][2] = b4.z; acc[r][3] = b4.w;
  }
#pragma unroll 4
  for (int k = 0; k < 128; ++k) {
    float4 w4 = *(const float4*)(W + k * 128 + j0);
#pragma unroll
    for (int r = 0; r < 4; ++r) {
      float xv = xs[tr * 4 + r][k];
      acc[r][0] = fmaf(xv, w4.x, acc[r][0]);
      acc[r][1] = fmaf(xv, w4.y, acc[r][1]);
      acc[r][2] = fmaf(xv, w4.z, acc[r][2]);
      acc[r][3] = fmaf(xv, w4.w, acc[r][3]);
    }
  }
#pragma unroll
  for (int r = 0; r < 4; ++r) {
    int row = rb + tr * 4 + r;
    if (row < n)
      *(float4*)(y + (size_t)row * 128 + j0) =
          make_float4(acc[r][0], acc[r][1], acc[r][2], acc[r][3]);
  }
}

extern "C" void kernel_launch(void* const* d_in, const int* in_sizes, int n_in,
                              void* d_out, int out_size, void* d_ws, size_t ws_size,
                              hipStream_t stream) {
  const int* labels = (const int*)d_in[0];
  const int* edge_index = (const int*)d_in[1];
  const float* weight = (const float*)d_in[2];
  const float* emb = (const float*)d_in[3];
  const float* W1 = (const float*)d_in[4];
  const float* b1 = (const float*)d_in[5];
  const float* W2 = (const float*)d_in[6];
  const float* b2 = (const float*)d_in[7];

  int n = in_sizes[0];
  int e = in_sizes[1] / 2;
  int vocab = in_sizes[3] / 128;
  const int* srcp = edge_index;
  const int* dstp = edge_index + e;

  // workspace carve-up (float elements, 256-aligned). Total ~46 MiB.
  float* ws = (float*)d_ws;
  size_t o = 0;
  auto alloc_f = [&](size_t c) { float* p = ws + o; o += (c + 255) & ~(size_t)255; return p; };
  int*   cnt   = (int*)alloc_f(n);
  int*   rank  = (int*)alloc_f(e);
  int*   rs    = (int*)alloc_f(n + 1);
  int*   bsum  = (int*)alloc_f(256);
  int2*  csr   = (int2*)alloc_f((size_t)e * 2);
  float* dinv  = alloc_f(n);
  float* temb  = alloc_f((size_t)vocab * 128);
  float* out1  = alloc_f((size_t)n * 128);
  (void)ws_size;

  dim3 b256(256);
  int gn = (n + 255) / 256;
  int ge = (e + 255) / 256;
  int nb = gn;  // scan blocks (196 for n=50000)
  int gagg = (int)(((size_t)n * 64 + 255) / 256);

  init_kernel<<<gn, b256, 0, stream>>>(cnt, n);
  rank_kernel<<<ge, b256, 0, stream>>>(dstp, cnt, rank, e);
  scan_a<<<nb, b256, 0, stream>>>(cnt, rs, bsum, n);
  scan_b<<<1, b256, 0, stream>>>(bsum, nb);
  scan_c<<<gn, b256, 0, stream>>>(bsum, rs, n, e);
  place_kernel<<<ge, b256, 0, stream>>>(srcp, dstp, weight, rank, rs, csr, e);
  deg_kernel<<<gagg, b256, 0, stream>>>(rs, csr, dinv, n);
  scale_kernel<<<ge, b256, 0, stream>>>(csr, dinv, e);
  temb_kernel<<<vocab, 128, 0, stream>>>(emb, W1, temb);
  // layer 1: out1 = relu(A_hat temb[labels] + b1)
  agg_kernel<true><<<gagg, b256, 0, stream>>>(rs, csr, dinv, labels, temb, b1, out1, n);
  // layer 2: d_out = (A_hat out1) @ W2 + b2   (agg first, then in-place GEMM)
  agg_kernel<false><<<gagg, b256, 0, stream>>>(rs, csr, dinv, labels, out1, nullptr,
                                               (float*)d_out, n);
  gemm_bias_kernel<<<(n + 31) / 32, b256, 0, stream>>>((float*)d_out, W2, b2, n);
}